// Round 1
// 182.410 us; speedup vs baseline: 1.0472x; 1.0472x over previous
//
#include <hip/hip_runtime.h>

#define A_N 1024
#define T_N 256
#define CS 384
#define CZ 128
#define CA 128
#define CP 16
#define LN_EPS 1e-5f

typedef __bf16  bf16x8 __attribute__((ext_vector_type(8)));
typedef float   f32x4  __attribute__((ext_vector_type(4)));

#define WSTRIDE 136   // bf16 elements per wb row (272 B, 16B-aligned)

// ============================================================================
// Kernel 1: fused token-space phase.
//   blocks [0,256):    s phase — Ys[t,:] = LN(s_trunk[t,:]) @ W_s
//                      (2-way K-split across 256 threads to halve the serial
//                       FMA/load chain and double occupancy vs old s_kernel)
//   blocks [256,1280): z phase — Yz = LN-folded MFMA projection, 64 token-pair
//                      rows per block, PLUS tok[a] recovery from one-hot a2t
//                      (a = blockIdx-256; 1024 z-blocks <-> 1024 atoms)
// ============================================================================
__global__ __launch_bounds__(256) void token_kernel(
        const float* __restrict__ s_trunk,
        const float* __restrict__ gs,
        const float* __restrict__ bs,
        const float* __restrict__ W_s,
        float* __restrict__ Ys,
        const float* __restrict__ zij,
        const float* __restrict__ gz,
        const float* __restrict__ bz,
        const float* __restrict__ W_z,
        float* __restrict__ Yz,
        const float* __restrict__ a2t,
        int* __restrict__ tok) {
    // shared for s path
    __shared__ float xs[CS];
    __shared__ float2 sred[4];
    __shared__ float part[2][128];
    // shared for z path
    __shared__ __bf16 wb[CP * WSTRIDE];     // wb[j][k] = bf16(gz[k]*W_z[k][j])
    __shared__ float2 gb_part[16][16];
    __shared__ float Gw_sh[CP], Bw_sh[CP];

    int tid = threadIdx.x;

    if (blockIdx.x < 256) {
        // ------------------------- s phase -------------------------
        int t = blockIdx.x;
        float sum = 0.f, sq = 0.f;
        {
            float v = s_trunk[t * CS + tid];
            xs[tid] = v; sum = v; sq = v * v;
            if (tid < CS - 256) {                 // tid < 128
                float v2 = s_trunk[t * CS + 256 + tid];
                xs[256 + tid] = v2; sum += v2; sq += v2 * v2;
            }
        }
        #pragma unroll
        for (int off = 32; off > 0; off >>= 1) {
            sum += __shfl_down(sum, off);
            sq  += __shfl_down(sq,  off);
        }
        if ((tid & 63) == 0) sred[tid >> 6] = make_float2(sum, sq);
        __syncthreads();
        float s_ = sred[0].x + sred[1].x + sred[2].x + sred[3].x;
        float ss = sred[0].y + sred[1].y + sred[2].y + sred[3].y;
        float m = s_ * (1.f / CS);
        float rstd = rsqrtf(ss * (1.f / CS) - m * m + LN_EPS);

        int col = tid & 127, seg = tid >> 7;      // 2 segs x 192 k's
        float a0 = 0.f, a1 = 0.f, a2 = 0.f, a3 = 0.f;
        int k0 = seg * (CS / 2);
        for (int k = k0; k < k0 + CS / 2; k += 4) {
            float z0 = (xs[k + 0] - m) * rstd * gs[k + 0] + bs[k + 0];
            float z1 = (xs[k + 1] - m) * rstd * gs[k + 1] + bs[k + 1];
            float z2 = (xs[k + 2] - m) * rstd * gs[k + 2] + bs[k + 2];
            float z3 = (xs[k + 3] - m) * rstd * gs[k + 3] + bs[k + 3];
            a0 = fmaf(z0, W_s[(k + 0) * CA + col], a0);
            a1 = fmaf(z1, W_s[(k + 1) * CA + col], a1);
            a2 = fmaf(z2, W_s[(k + 2) * CA + col], a2);
            a3 = fmaf(z3, W_s[(k + 3) * CA + col], a3);
        }
        part[seg][col] = (a0 + a1) + (a2 + a3);
        __syncthreads();
        if (tid < 128) Ys[t * CA + tid] = part[0][tid] + part[1][tid];
        return;
    }

    // ------------------------- z phase (+ tok) -------------------------
    int a = blockIdx.x - 256;

    // tok recovery: block a scans one-hot row a2t[a,:] (1 KB, coalesced)
    { float v = a2t[(size_t)a * T_N + tid]; if (v > 0.5f) tok[a] = tid; }

    // stage Wg^T (bf16) + Gw/Bw partials
    {
        int j = tid & 15, seg = tid >> 4;       // 16 segs x 8 k's
        float sg = 0.f, sb = 0.f;
        #pragma unroll
        for (int i = 0; i < 8; ++i) {
            int k = seg * 8 + i;
            float w = W_z[k * CP + j];
            float gw = gz[k] * w;
            wb[j * WSTRIDE + k] = (__bf16)gw;
            sg += gw;
            sb = fmaf(bz[k], w, sb);
        }
        gb_part[seg][j] = make_float2(sg, sb);
    }
    __syncthreads();
    if (tid < CP) {
        float sg = 0.f, sb = 0.f;
        #pragma unroll
        for (int s = 0; s < 16; ++s) { float2 p = gb_part[s][tid]; sg += p.x; sb += p.y; }
        Gw_sh[tid] = sg; Bw_sh[tid] = sb;
    }

    int wave = tid >> 6, lane = tid & 63;
    int m    = lane & 15, quad = lane >> 4;
    size_t grow = (size_t)a * 64 + wave * 16 + m;   // token-pair row this lane loads

    // load X tile rows straight into registers (A-frag pattern)
    const float4* zrow = (const float4*)(zij + grow * CZ);
    float4 xv[8];
    #pragma unroll
    for (int s = 0; s < 4; ++s) {
        xv[2 * s]     = zrow[quad * 2 + 8 * s];
        xv[2 * s + 1] = zrow[quad * 2 + 8 * s + 1];
    }

    // LN stats for row m: per-lane partial over 32 elems, reduce across quads
    float sum = 0.f, sq = 0.f;
    #pragma unroll
    for (int i = 0; i < 8; ++i) {
        float4 v = xv[i];
        sum += (v.x + v.y) + (v.z + v.w);
        sq  += v.x * v.x + v.y * v.y + v.z * v.z + v.w * v.w;
    }
    sum += __shfl_xor(sum, 16);  sq += __shfl_xor(sq, 16);
    sum += __shfl_xor(sum, 32);  sq += __shfl_xor(sq, 32);
    float mval = sum * (1.f / CZ);
    float rstd = rsqrtf(sq * (1.f / CZ) - mval * mval + LN_EPS);

    __syncthreads();   // wb/Gw/Bw ready

    // MFMA over 4 K-steps
    f32x4 acc = {0.f, 0.f, 0.f, 0.f};
    #pragma unroll
    for (int s = 0; s < 4; ++s) {
        float4 v0 = xv[2 * s], v1 = xv[2 * s + 1];
        bf16x8 af;
        af[0] = (__bf16)v0.x; af[1] = (__bf16)v0.y;
        af[2] = (__bf16)v0.z; af[3] = (__bf16)v0.w;
        af[4] = (__bf16)v1.x; af[5] = (__bf16)v1.y;
        af[6] = (__bf16)v1.z; af[7] = (__bf16)v1.w;
        bf16x8 bfv = *(const bf16x8*)&wb[m * WSTRIDE + quad * 8 + 32 * s];
        acc = __builtin_amdgcn_mfma_f32_16x16x32_bf16(af, bfv, acc, 0, 0, 0);
    }

    // epilogue: C layout row = quad*4+i, col = m
    float gwj = Gw_sh[m], bwj = Bw_sh[m];
    size_t obase = (size_t)a * 64 + wave * 16;
    #pragma unroll
    for (int i = 0; i < 4; ++i) {
        int r = quad * 4 + i;
        float mi = __shfl(mval, r);     // stats live in lanes 0..15 (lane&15 == row)
        float ri = __shfl(rstd, r);
        float y = ri * (acc[i] - mi * gwj) + bwj;
        Yz[(obase + r) * CP + m] = y;
    }
}

// ============================================================================
// Kernel 2: per-atom-row fused output. One block per atom a (1024 x 512 thr):
//   - stage tok[0..1023] (4 KB) and the full Yz[ta,:,:] slice (16 KB,
//     XOR-swizzled for bank spread) in LDS
//   - cl/ql rows (threads 0..255)
//   - plm row stream: out[a,b,:] = plm[a,b,:] + lds_gather(tok[b])
//     -> pure 128 MB HBM stream, no global gather
// ============================================================================
__global__ __launch_bounds__(512) void atom_plm_kernel(
        const float* __restrict__ plm,
        const float* __restrict__ Yz,
        const int* __restrict__ tok,
        const float* __restrict__ cl,
        const float* __restrict__ ql,
        const float* __restrict__ rl,
        const float* __restrict__ Ys,
        const float* __restrict__ W_r,
        float* __restrict__ out_cl,
        float* __restrict__ out_plm,
        float* __restrict__ out_ql) {
    __shared__ int    tok_sh[A_N];                 // 4 KB
    __shared__ float4 yz_sh[T_N * CP / 4];         // 16 KB, swizzled

    int a = blockIdx.x;
    int tid = threadIdx.x;
    int ta = tok[a];                               // block-uniform

    // stage tok[] (1024 ints = 256 int4)
    if (tid < 256) ((int4*)tok_sh)[tid] = ((const int4*)tok)[tid];

    // stage Yz[ta,:,:] (4096 floats = 1024 float4), swizzle idx^((idx>>3)&7)
    const float4* yrow = (const float4*)(Yz + (size_t)ta * (T_N * CP));
    #pragma unroll
    for (int p = 0; p < 2; ++p) {
        int j = p * 512 + tid;
        yz_sh[j ^ ((j >> 3) & 7)] = yrow[j];
    }

    // cl / ql rows (independent of the staging)
    if (tid < 128) {
        out_cl[a * CA + tid] = cl[a * CA + tid] + Ys[ta * CA + tid];
    } else if (tid < 256) {
        int c = tid - 128;
        float r0 = rl[a * 3 + 0], r1 = rl[a * 3 + 1], r2 = rl[a * 3 + 2];
        out_ql[a * CA + c] = ql[a * CA + c]
            + fmaf(r0, W_r[c], fmaf(r1, W_r[CA + c], r2 * W_r[2 * CA + c]));
    }
    __syncthreads();

    // plm row stream: 4096 float4s, 512 threads x 8 iters, fully coalesced
    const float4* prow = (const float4*)(plm     + (size_t)a * (A_N * CP));
    float4*       orow = (float4*)      (out_plm + (size_t)a * (A_N * CP));
    #pragma unroll
    for (int it = 0; it < 8; ++it) {
        int f4 = it * 512 + tid;
        int b  = f4 >> 2;                          // 4 float4s per b
        int tb = tok_sh[b];                        // broadcast within 4-lane group
        int x  = tb * 4 + (f4 & 3);
        float4 yv = yz_sh[x ^ ((x >> 3) & 7)];
        float4 pv = prow[f4];
        float4 o;
        o.x = pv.x + yv.x; o.y = pv.y + yv.y;
        o.z = pv.z + yv.z; o.w = pv.w + yv.w;
        orow[f4] = o;
    }
}

extern "C" void kernel_launch(void* const* d_in, const int* in_sizes, int n_in,
                              void* d_out, int out_size, void* d_ws, size_t ws_size,
                              hipStream_t stream) {
    const float* a2t     = (const float*)d_in[0];
    const float* cl      = (const float*)d_in[1];
    const float* plm     = (const float*)d_in[2];
    const float* ql      = (const float*)d_in[3];
    const float* s_trunk = (const float*)d_in[4];
    const float* zij     = (const float*)d_in[5];
    const float* rl      = (const float*)d_in[6];
    const float* ln_s_g  = (const float*)d_in[7];
    const float* ln_s_b  = (const float*)d_in[8];
    const float* W_s     = (const float*)d_in[9];
    const float* ln_z_g  = (const float*)d_in[10];
    const float* ln_z_b  = (const float*)d_in[11];
    const float* W_z     = (const float*)d_in[12];
    const float* W_r     = (const float*)d_in[13];

    // workspace layout
    int*   tok = (int*)d_ws;                            // 4 KB
    float* Ys  = (float*)((char*)d_ws + 4096);          // 256*128 floats (128 KB)
    float* Yz  = (float*)((char*)d_ws + 4096 + 131072); // 65536*16 floats (4 MB)

    // output layout: cl [1024*128], plm [1024*1024*16], ql [1024*128]
    float* out_cl  = (float*)d_out;
    float* out_plm = out_cl + A_N * CA;
    float* out_ql  = out_plm + (size_t)A_N * A_N * CP;

    token_kernel<<<256 + A_N, 256, 0, stream>>>(
        s_trunk, ln_s_g, ln_s_b, W_s, Ys,
        zij, ln_z_g, ln_z_b, W_z, Yz,
        a2t, tok);
    atom_plm_kernel<<<A_N, 512, 0, stream>>>(
        plm, Yz, tok, cl, ql, rl, Ys, W_r,
        out_cl, out_plm, out_ql);
}